// Round 1
// baseline (155.121 us; speedup 1.0000x reference)
//
#include <hip/hip_runtime.h>
#include <hip/hip_bf16.h>
#include <math.h>

// Problem constants
constexpr int kB  = 8;
constexpr int kTD = 128;
constexpr int kTE = 256;
constexpr int kH  = 512;

constexpr float kTwoLog2e = 2.8853900817779268f; // 2*log2(e), folded into GEMM epilogue
constexpr float kLog2e    = 1.4426950408889634f;

// tanh(x) from pre-scaled input xs = 2*log2(e)*x:
//   e = 2^xs = e^(2x);  tanh(x) = 1 - 2/(e+1)
__device__ __forceinline__ float tanh_from_scaled(float xs) {
    float e = __builtin_amdgcn_exp2f(xs);
    float r = __builtin_amdgcn_rcpf(e + 1.0f);
    return fmaf(-2.0f, r, 1.0f);
}

// ---------------------------------------------------------------------------
// Kernel 0: decode the boolean mask (layout auto-detect: int32 / byte / float)
// ---------------------------------------------------------------------------
__global__ void mask_decode_kernel(const void* __restrict__ mask_raw,
                                   float* __restrict__ mask_f) {
    const int tid = threadIdx.x;
    const unsigned int* w = (const unsigned int*)mask_raw;
    // First 512 words (2048 bytes) are safe to read under every candidate layout.
    unsigned int gt1 = 0, flt = 0;
    for (int i = tid; i < 512; i += 256) {
        unsigned int v = w[i];
        if (v == 0x3f800000u) flt = 1;       // float 1.0f -> float32 layout
        else if (v > 1u) gt1 = 1;            // packed bytes -> byte layout
    }
    __shared__ unsigned int s_gt1, s_flt;
    if (tid == 0) { s_gt1 = 0u; s_flt = 0u; }
    __syncthreads();
    if (gt1) atomicOr(&s_gt1, 1u);
    if (flt) atomicOr(&s_flt, 1u);
    __syncthreads();
    const int mode = s_flt ? 2 : (s_gt1 ? 1 : 0);

    for (int i = tid; i < kB * kTE; i += 256) {
        float val;
        if (mode == 2)      val = ((const float*)mask_raw)[i];
        else if (mode == 1) val = (float)(((const unsigned char*)mask_raw)[i]);
        else                val = (float)(((const int*)mask_raw)[i]);
        mask_f[i] = val;
    }
}

// ---------------------------------------------------------------------------
// Kernel 1: C[M,512] = scale * A[M,512] @ W[512,512]   (fp32 tiled GEMM)
// ---------------------------------------------------------------------------
constexpr int BM = 64, BN = 64, BK = 16;

__global__ __launch_bounds__(256)
void gemm_scaled_kernel(const float* __restrict__ A, const float* __restrict__ W,
                        float* __restrict__ C, float scale) {
    __shared__ float As[BK][BM + 4];  // +4 pad keeps 16B alignment, breaks bank stride
    __shared__ float Bs[BK][BN];

    const int tid = threadIdx.x;
    const int tx = tid & 15;          // 0..15 -> output col group
    const int ty = tid >> 4;          // 0..15 -> output row group
    const int m0 = blockIdx.x * BM;
    const int n0 = blockIdx.y * BN;

    const int ar  = tid >> 2;         // 0..63  A-tile row
    const int ac4 = tid & 3;          // 0..3   A-tile float4 col

    float acc[4][4] = {};

    for (int k0 = 0; k0 < kH; k0 += BK) {
        // A tile 64x16 via one float4/thread (coalesced in 64B granules)
        float4 av = *(const float4*)&A[(m0 + ar) * kH + k0 + ac4 * 4];
        // W tile 16x64, 4 rows per pass, fully coalesced
        #pragma unroll
        for (int it = 0; it < 4; ++it) {
            int idx = it * 256 + tid;
            int r = idx >> 6, c = idx & 63;
            Bs[r][c] = W[(k0 + r) * kH + n0 + c];
        }
        // store A transposed: As[k][m]
        As[ac4 * 4 + 0][ar] = av.x;
        As[ac4 * 4 + 1][ar] = av.y;
        As[ac4 * 4 + 2][ar] = av.z;
        As[ac4 * 4 + 3][ar] = av.w;
        __syncthreads();

        #pragma unroll
        for (int kk = 0; kk < BK; ++kk) {
            float4 a  = *(const float4*)&As[kk][ty * 4];
            float4 bq = *(const float4*)&Bs[kk][tx * 4];
            float avv[4] = {a.x, a.y, a.z, a.w};
            float bvv[4] = {bq.x, bq.y, bq.z, bq.w};
            #pragma unroll
            for (int i = 0; i < 4; ++i)
                #pragma unroll
                for (int j = 0; j < 4; ++j)
                    acc[i][j] = fmaf(avv[i], bvv[j], acc[i][j]);
        }
        __syncthreads();
    }

    #pragma unroll
    for (int i = 0; i < 4; ++i) {
        float4 o;
        o.x = acc[i][0] * scale;
        o.y = acc[i][1] * scale;
        o.z = acc[i][2] * scale;
        o.w = acc[i][3] * scale;
        *(float4*)&C[(m0 + ty * 4 + i) * kH + n0 + tx * 4] = o;
    }
}

// ---------------------------------------------------------------------------
// Kernel 2: fused score -> softmax -> context for one (b, t) per block.
//   phase 1: thread = s (256 threads), score_s = sum_h V_h*tanh(ewc+dwc)
//   phase 2: softmax over s (wave shfl + LDS combine)
//   phase 3: thread = h, ctx[h] = sum_s w_s * enc[b,s,h]
// ---------------------------------------------------------------------------
__global__ __launch_bounds__(256)
void fused_attn_kernel(const float* __restrict__ ewc, const float* __restrict__ dwc,
                       const float* __restrict__ enc, const float* __restrict__ V,
                       const float* __restrict__ mask_f,
                       float* __restrict__ ctx_out, float* __restrict__ attn_out) {
    const int t = blockIdx.x;
    const int b = blockIdx.y;
    const int tid = threadIdx.x;

    __shared__ float dw_s[kH];
    __shared__ float v_s[kH];
    __shared__ float w_s[kTE];
    __shared__ float red[8];

    const float* dwrow = dwc + (b * kTD + t) * kH;
    for (int i = tid; i < kH; i += 256) {
        dw_s[i] = dwrow[i];
        v_s[i]  = V[i];
    }
    __syncthreads();

    // ---- phase 1: scores (thread owns s = tid) ----
    const int s = tid;
    const float4* ewrow = (const float4*)(ewc + (b * kTE + s) * kH);
    const float4* dw4 = (const float4*)dw_s;
    const float4* v4  = (const float4*)v_s;

    float score = 0.0f;
    #pragma unroll 4
    for (int h4 = 0; h4 < kH / 4; ++h4) {
        float4 e  = ewrow[h4];
        float4 d  = dw4[h4];
        float4 vv = v4[h4];
        score = fmaf(vv.x, tanh_from_scaled(e.x + d.x), score);
        score = fmaf(vv.y, tanh_from_scaled(e.y + d.y), score);
        score = fmaf(vv.z, tanh_from_scaled(e.z + d.z), score);
        score = fmaf(vv.w, tanh_from_scaled(e.w + d.w), score);
    }

    const float m = mask_f[b * kTE + s];
    score = fmaf(1.0f - m, -1e9f, score);   // exact reference masking formula

    // ---- phase 2: softmax over 256 s ----
    float mx = score;
    #pragma unroll
    for (int off = 1; off < 64; off <<= 1)
        mx = fmaxf(mx, __shfl_xor(mx, off));
    const int wid = tid >> 6;
    if ((tid & 63) == 0) red[wid] = mx;
    __syncthreads();
    mx = fmaxf(fmaxf(red[0], red[1]), fmaxf(red[2], red[3]));

    float p = __builtin_amdgcn_exp2f((score - mx) * kLog2e);
    float sum = p;
    #pragma unroll
    for (int off = 1; off < 64; off <<= 1)
        sum += __shfl_xor(sum, off);
    if ((tid & 63) == 0) red[4 + wid] = sum;
    __syncthreads();
    sum = (red[4] + red[5]) + (red[6] + red[7]);

    const float wgt = p / sum;
    attn_out[(b * kTD + t) * kTE + s] = wgt;
    w_s[s] = wgt;
    __syncthreads();

    // ---- phase 3: context (thread owns h = tid, tid+256) ----
    const float* encb = enc + b * kTE * kH;
    float acc0 = 0.0f, acc1 = 0.0f;
    #pragma unroll 4
    for (int ss = 0; ss < kTE; ++ss) {
        float wv = w_s[ss];
        acc0 = fmaf(wv, encb[ss * kH + tid], acc0);
        acc1 = fmaf(wv, encb[ss * kH + tid + 256], acc1);
    }
    float* crow = ctx_out + (b * kTD + t) * kH;
    crow[tid]       = acc0;
    crow[tid + 256] = acc1;
}

// ---------------------------------------------------------------------------
extern "C" void kernel_launch(void* const* d_in, const int* in_sizes, int n_in,
                              void* d_out, int out_size, void* d_ws, size_t ws_size,
                              hipStream_t stream) {
    const float* enc  = (const float*)d_in[0];   // [B, TE, H]
    const float* dec  = (const float*)d_in[1];   // [B, TD, H]
    const void*  mask = d_in[2];                 // [B, TE] bool (layout auto-detected)
    const float* W1   = (const float*)d_in[3];   // [H, H]
    const float* W2   = (const float*)d_in[4];   // [H, H]
    const float* V    = (const float*)d_in[5];   // [H, 1]

    float* ctx_out  = (float*)d_out;                     // [B, TD, H]
    float* attn_out = (float*)d_out + kB * kTD * kH;     // [B, TD, TE]

    char* ws = (char*)d_ws;
    float* mask_f = (float*)ws;                                   // 2048 f
    float* ewc    = (float*)(ws + 8192);                          // [B*TE, H]
    float* dwc    = (float*)(ws + 8192 + (size_t)kB * kTE * kH * 4); // [B*TD, H]

    hipLaunchKernelGGL(mask_decode_kernel, dim3(1), dim3(256), 0, stream,
                       mask, mask_f);
    hipLaunchKernelGGL(gemm_scaled_kernel, dim3(kB * kTE / BM, kH / BN), dim3(256),
                       0, stream, enc, W1, ewc, kTwoLog2e);
    hipLaunchKernelGGL(gemm_scaled_kernel, dim3(kB * kTD / BM, kH / BN), dim3(256),
                       0, stream, dec, W2, dwc, kTwoLog2e);
    hipLaunchKernelGGL(fused_attn_kernel, dim3(kTD, kB), dim3(256), 0, stream,
                       ewc, dwc, enc, V, mask_f, ctx_out, attn_out);
}

// Round 2
// 77.620 us; speedup vs baseline: 1.9985x; 1.9985x over previous
//
#include <hip/hip_runtime.h>
#include <hip/hip_bf16.h>
#include <math.h>

// Problem constants
constexpr int kB  = 8;
constexpr int kTD = 128;
constexpr int kTE = 256;
constexpr int kH  = 512;

constexpr float kTwoLog2e = 2.8853900817779268f; // 2*log2(e)
constexpr float kLog2e    = 1.4426950408889634f;

constexpr int TM = 4;              // t-tile in fused kernel
constexpr int GEMM_BLOCKS = 384;   // 256 (enc) + 128 (dec)

// ---------------------------------------------------------------------------
// Kernel 1 (prep): both GEMMs with exp2 epilogue + mask decode, one launch.
//   C[m,n] = exp2( 2*log2e * sum_k A[m,k]*W[k,n] )  == e^{2*(A@W)[m,n]}
// ---------------------------------------------------------------------------
__global__ __launch_bounds__(256)
void prep_kernel(const float* __restrict__ enc, const float* __restrict__ dec,
                 const float* __restrict__ W1, const float* __restrict__ W2,
                 const void* __restrict__ mask_raw,
                 float* __restrict__ ewc, float* __restrict__ dwc,
                 float* __restrict__ mask_f) {
    const int bx = blockIdx.x;
    const int tid = threadIdx.x;

    if (bx == GEMM_BLOCKS) {
        // ---- mask decode (layout auto-detect: int32 / byte / float) ----
        const unsigned int* w = (const unsigned int*)mask_raw;
        unsigned int gt1 = 0, flt = 0;
        for (int i = tid; i < 512; i += 256) {
            unsigned int v = w[i];
            if (v == 0x3f800000u) flt = 1;
            else if (v > 1u) gt1 = 1;
        }
        __shared__ unsigned int s_gt1, s_flt;
        if (tid == 0) { s_gt1 = 0u; s_flt = 0u; }
        __syncthreads();
        if (gt1) atomicOr(&s_gt1, 1u);
        if (flt) atomicOr(&s_flt, 1u);
        __syncthreads();
        const int mode = s_flt ? 2 : (s_gt1 ? 1 : 0);
        for (int i = tid; i < kB * kTE; i += 256) {
            float val;
            if (mode == 2)      val = ((const float*)mask_raw)[i];
            else if (mode == 1) val = (float)(((const unsigned char*)mask_raw)[i]);
            else                val = (float)(((const int*)mask_raw)[i]);
            mask_f[i] = val;
        }
        return;
    }

    // ---- GEMM: 64x64 tile, BK=32, 4x4 acc ----
    const float* A; const float* W; float* C; int m0, n0;
    if (bx < 256) { A = enc; W = W1; C = ewc; m0 = (bx >> 3) * 64; n0 = (bx & 7) * 64; }
    else { int b2 = bx - 256; A = dec; W = W2; C = dwc; m0 = (b2 >> 3) * 64; n0 = (b2 & 7) * 64; }

    __shared__ float As[32][68];   // [k][m], pad 68 keeps 16B alignment
    __shared__ float Bs[32][64];   // [k][n]

    const int tx = tid & 15;       // 0..15 -> col quad
    const int ty = tid >> 4;       // 0..15 -> row quad
    float acc[4][4] = {};

    for (int k0 = 0; k0 < kH; k0 += 32) {
        #pragma unroll
        for (int p = 0; p < 2; ++p) {           // A: 64 rows x 32 k
            int i = tid + p * 256;
            int r = i >> 3, c4 = i & 7;
            float4 av = *(const float4*)&A[(size_t)(m0 + r) * kH + k0 + c4 * 4];
            As[c4 * 4 + 0][r] = av.x;
            As[c4 * 4 + 1][r] = av.y;
            As[c4 * 4 + 2][r] = av.z;
            As[c4 * 4 + 3][r] = av.w;
        }
        #pragma unroll
        for (int p = 0; p < 2; ++p) {           // B: 32 k x 64 n
            int i = tid + p * 256;
            int kr = i >> 4, c4 = i & 15;
            *(float4*)&Bs[kr][c4 * 4] =
                *(const float4*)&W[(size_t)(k0 + kr) * kH + n0 + c4 * 4];
        }
        __syncthreads();

        #pragma unroll
        for (int kk = 0; kk < 32; ++kk) {
            float4 a  = *(const float4*)&As[kk][ty * 4];
            float4 bq = *(const float4*)&Bs[kk][tx * 4];
            float av[4] = {a.x, a.y, a.z, a.w};
            float bv[4] = {bq.x, bq.y, bq.z, bq.w};
            #pragma unroll
            for (int i = 0; i < 4; ++i)
                #pragma unroll
                for (int j = 0; j < 4; ++j)
                    acc[i][j] = fmaf(av[i], bv[j], acc[i][j]);
        }
        __syncthreads();
    }

    #pragma unroll
    for (int i = 0; i < 4; ++i) {
        float4 o;
        o.x = __builtin_amdgcn_exp2f(acc[i][0] * kTwoLog2e);
        o.y = __builtin_amdgcn_exp2f(acc[i][1] * kTwoLog2e);
        o.z = __builtin_amdgcn_exp2f(acc[i][2] * kTwoLog2e);
        o.w = __builtin_amdgcn_exp2f(acc[i][3] * kTwoLog2e);
        *(float4*)&C[(size_t)(m0 + ty * 4 + i) * kH + n0 + tx * 4] = o;
    }
}

// ---------------------------------------------------------------------------
// Kernel 2 (fused): scores -> softmax -> context for a (b, 4-t tile) per block.
//   512 threads: s = tid&255, hh = tid>>8 (h-half).
//   tanh(ew+dw) = 1 - 2/(E*P+1) with E,P pre-exponentiated by prep_kernel.
//   score_t = SV - 2 * sum_h V_h / (E_h*P_{t,h} + 1)
// ---------------------------------------------------------------------------
__global__ __launch_bounds__(512)
void fused_attn_kernel(const float* __restrict__ ewc, const float* __restrict__ dwc,
                       const float* __restrict__ enc, const float* __restrict__ V,
                       const float* __restrict__ mask_f,
                       float* __restrict__ ctx_out, float* __restrict__ attn_out) {
    const int t0  = blockIdx.x * TM;
    const int b   = blockIdx.y;
    const int tid = threadIdx.x;
    const int s   = tid & 255;
    const int hh  = tid >> 8;

    __shared__ float p_s[TM][kH];        // P rows (pre-exponentiated dw)
    __shared__ float v_s[kH];
    __shared__ float part[TM][256];      // h-half partial sums
    __shared__ float4 wgt4[256];         // softmax weights, t-major float4
    __shared__ float red_mx[4][TM], red_sm[4][TM];
    __shared__ float sv_red;

    // stage P (4 rows) and V
    {
        const float4* src = (const float4*)(dwc + (size_t)(b * kTD + t0) * kH);
        ((float4*)&p_s[0][0])[tid] = src[tid];          // TM*kH/4 = 512 float4s
        if (tid < kH / 4) ((float4*)v_s)[tid] = ((const float4*)V)[tid];
    }
    __syncthreads();

    // SV = sum_h V_h (wave 0 only; consumed after the next barrier)
    if (tid < 64) {
        float sv = 0.0f;
        #pragma unroll
        for (int k = 0; k < 8; ++k) sv += v_s[tid + k * 64];
        #pragma unroll
        for (int off = 1; off < 64; off <<= 1) sv += __shfl_xor(sv, off);
        if (tid == 0) sv_red = sv;
    }

    // ---- score phase: acc_t = sum over this h-half of V_h / (E*P + 1) ----
    const float4* E4 = (const float4*)(ewc + (size_t)(b * kTE + s) * kH) + hh * 64;
    const float4* V4 = (const float4*)v_s + hh * 64;
    const float4* P0 = (const float4*)&p_s[0][0] + hh * 64;
    const float4* P1 = (const float4*)&p_s[1][0] + hh * 64;
    const float4* P2 = (const float4*)&p_s[2][0] + hh * 64;
    const float4* P3 = (const float4*)&p_s[3][0] + hh * 64;

    float a0 = 0.0f, a1 = 0.0f, a2 = 0.0f, a3 = 0.0f;
    #pragma unroll 4
    for (int i = 0; i < 64; ++i) {
        float4 e  = E4[i];
        float4 vv = V4[i];
        float4 q0 = P0[i], q1 = P1[i], q2 = P2[i], q3 = P3[i];
        a0 = fmaf(vv.x, __builtin_amdgcn_rcpf(fmaf(e.x, q0.x, 1.0f)), a0);
        a1 = fmaf(vv.x, __builtin_amdgcn_rcpf(fmaf(e.x, q1.x, 1.0f)), a1);
        a2 = fmaf(vv.x, __builtin_amdgcn_rcpf(fmaf(e.x, q2.x, 1.0f)), a2);
        a3 = fmaf(vv.x, __builtin_amdgcn_rcpf(fmaf(e.x, q3.x, 1.0f)), a3);
        a0 = fmaf(vv.y, __builtin_amdgcn_rcpf(fmaf(e.y, q0.y, 1.0f)), a0);
        a1 = fmaf(vv.y, __builtin_amdgcn_rcpf(fmaf(e.y, q1.y, 1.0f)), a1);
        a2 = fmaf(vv.y, __builtin_amdgcn_rcpf(fmaf(e.y, q2.y, 1.0f)), a2);
        a3 = fmaf(vv.y, __builtin_amdgcn_rcpf(fmaf(e.y, q3.y, 1.0f)), a3);
        a0 = fmaf(vv.z, __builtin_amdgcn_rcpf(fmaf(e.z, q0.z, 1.0f)), a0);
        a1 = fmaf(vv.z, __builtin_amdgcn_rcpf(fmaf(e.z, q1.z, 1.0f)), a1);
        a2 = fmaf(vv.z, __builtin_amdgcn_rcpf(fmaf(e.z, q2.z, 1.0f)), a2);
        a3 = fmaf(vv.z, __builtin_amdgcn_rcpf(fmaf(e.z, q3.z, 1.0f)), a3);
        a0 = fmaf(vv.w, __builtin_amdgcn_rcpf(fmaf(e.w, q0.w, 1.0f)), a0);
        a1 = fmaf(vv.w, __builtin_amdgcn_rcpf(fmaf(e.w, q1.w, 1.0f)), a1);
        a2 = fmaf(vv.w, __builtin_amdgcn_rcpf(fmaf(e.w, q2.w, 1.0f)), a2);
        a3 = fmaf(vv.w, __builtin_amdgcn_rcpf(fmaf(e.w, q3.w, 1.0f)), a3);
    }

    if (hh == 1) {
        part[0][s] = a0; part[1][s] = a1; part[2][s] = a2; part[3][s] = a3;
    }
    __syncthreads();

    const bool active = (hh == 0);
    const int wv = s >> 6;          // wave id among the 4 active waves
    float sc0, sc1, sc2, sc3;
    if (active) {
        const float sv = sv_red;
        const float pen = (1.0f - mask_f[b * kTE + s]) * -1e9f;
        sc0 = fmaf(-2.0f, a0 + part[0][s], sv) + pen;
        sc1 = fmaf(-2.0f, a1 + part[1][s], sv) + pen;
        sc2 = fmaf(-2.0f, a2 + part[2][s], sv) + pen;
        sc3 = fmaf(-2.0f, a3 + part[3][s], sv) + pen;
        float m0 = sc0, m1 = sc1, m2 = sc2, m3 = sc3;
        #pragma unroll
        for (int off = 1; off < 64; off <<= 1) {
            m0 = fmaxf(m0, __shfl_xor(m0, off));
            m1 = fmaxf(m1, __shfl_xor(m1, off));
            m2 = fmaxf(m2, __shfl_xor(m2, off));
            m3 = fmaxf(m3, __shfl_xor(m3, off));
        }
        if ((s & 63) == 0) {
            red_mx[wv][0] = m0; red_mx[wv][1] = m1;
            red_mx[wv][2] = m2; red_mx[wv][3] = m3;
        }
    }
    __syncthreads();

    float p0, p1, p2, p3;
    if (active) {
        float m0 = fmaxf(fmaxf(red_mx[0][0], red_mx[1][0]), fmaxf(red_mx[2][0], red_mx[3][0]));
        float m1 = fmaxf(fmaxf(red_mx[0][1], red_mx[1][1]), fmaxf(red_mx[2][1], red_mx[3][1]));
        float m2 = fmaxf(fmaxf(red_mx[0][2], red_mx[1][2]), fmaxf(red_mx[2][2], red_mx[3][2]));
        float m3 = fmaxf(fmaxf(red_mx[0][3], red_mx[1][3]), fmaxf(red_mx[2][3], red_mx[3][3]));
        p0 = __builtin_amdgcn_exp2f((sc0 - m0) * kLog2e);
        p1 = __builtin_amdgcn_exp2f((sc1 - m1) * kLog2e);
        p2 = __builtin_amdgcn_exp2f((sc2 - m2) * kLog2e);
        p3 = __builtin_amdgcn_exp2f((sc3 - m3) * kLog2e);
        float s0 = p0, s1 = p1, s2 = p2, s3 = p3;
        #pragma unroll
        for (int off = 1; off < 64; off <<= 1) {
            s0 += __shfl_xor(s0, off);
            s1 += __shfl_xor(s1, off);
            s2 += __shfl_xor(s2, off);
            s3 += __shfl_xor(s3, off);
        }
        if ((s & 63) == 0) {
            red_sm[wv][0] = s0; red_sm[wv][1] = s1;
            red_sm[wv][2] = s2; red_sm[wv][3] = s3;
        }
    }
    __syncthreads();

    if (active) {
        float s0 = (red_sm[0][0] + red_sm[1][0]) + (red_sm[2][0] + red_sm[3][0]);
        float s1 = (red_sm[0][1] + red_sm[1][1]) + (red_sm[2][1] + red_sm[3][1]);
        float s2 = (red_sm[0][2] + red_sm[1][2]) + (red_sm[2][2] + red_sm[3][2]);
        float s3 = (red_sm[0][3] + red_sm[1][3]) + (red_sm[2][3] + red_sm[3][3]);
        float4 w;
        w.x = p0 * __builtin_amdgcn_rcpf(s0);
        w.y = p1 * __builtin_amdgcn_rcpf(s1);
        w.z = p2 * __builtin_amdgcn_rcpf(s2);
        w.w = p3 * __builtin_amdgcn_rcpf(s3);
        wgt4[s] = w;
        float* ao = attn_out + (size_t)(b * kTD + t0) * kTE + s;
        ao[0]        = w.x;
        ao[kTE]      = w.y;
        ao[2 * kTE]  = w.z;
        ao[3 * kTE]  = w.w;
    }
    __syncthreads();

    // ---- context phase: thread owns h = tid (512 h) ----
    const float* encb = enc + (size_t)b * kTE * kH + tid;
    float c0 = 0.0f, c1 = 0.0f, c2 = 0.0f, c3 = 0.0f;
    #pragma unroll 4
    for (int ss = 0; ss < kTE; ++ss) {
        float e = encb[(size_t)ss * kH];
        float4 w = wgt4[ss];
        c0 = fmaf(w.x, e, c0);
        c1 = fmaf(w.y, e, c1);
        c2 = fmaf(w.z, e, c2);
        c3 = fmaf(w.w, e, c3);
    }
    float* co = ctx_out + (size_t)(b * kTD + t0) * kH + tid;
    co[0]       = c0;
    co[kH]      = c1;
    co[2 * kH]  = c2;
    co[3 * kH]  = c3;
}

// ---------------------------------------------------------------------------
extern "C" void kernel_launch(void* const* d_in, const int* in_sizes, int n_in,
                              void* d_out, int out_size, void* d_ws, size_t ws_size,
                              hipStream_t stream) {
    const float* enc  = (const float*)d_in[0];   // [B, TE, H]
    const float* dec  = (const float*)d_in[1];   // [B, TD, H]
    const void*  mask = d_in[2];                 // [B, TE] bool
    const float* W1   = (const float*)d_in[3];
    const float* W2   = (const float*)d_in[4];
    const float* V    = (const float*)d_in[5];   // [H, 1]

    float* ctx_out  = (float*)d_out;                     // [B, TD, H]
    float* attn_out = (float*)d_out + kB * kTD * kH;     // [B, TD, TE]

    char* ws = (char*)d_ws;
    float* mask_f = (float*)ws;                                      // 2048 f
    float* ewc    = (float*)(ws + 8192);                             // E = e^{2*ew}
    float* dwc    = (float*)(ws + 8192 + (size_t)kB * kTE * kH * 4); // P = e^{2*dw}

    hipLaunchKernelGGL(prep_kernel, dim3(GEMM_BLOCKS + 1), dim3(256), 0, stream,
                       enc, dec, W1, W2, mask, ewc, dwc, mask_f);
    hipLaunchKernelGGL(fused_attn_kernel, dim3(kTD / TM, kB), dim3(512), 0, stream,
                       ewc, dwc, enc, V, mask_f, ctx_out, attn_out);
}

// Round 3
// 71.661 us; speedup vs baseline: 2.1647x; 1.0832x over previous
//
#include <hip/hip_runtime.h>
#include <hip/hip_bf16.h>
#include <math.h>

// Problem constants
constexpr int kB  = 8;
constexpr int kTD = 128;
constexpr int kTE = 256;
constexpr int kH  = 512;

constexpr float kTwoLog2e = 2.8853900817779268f; // 2*log2(e)
constexpr float kLog2e    = 1.4426950408889634f;

constexpr int TM = 4;              // t-tile in fused kernel
constexpr int GEMM_BLOCKS = 384;   // 256 (enc) + 128 (dec)

// ---------------------------------------------------------------------------
// Kernel 1 (prep): both GEMMs (64x64 tile, 512 threads, K split in halves)
// with exp2 epilogue + mask decode. enc results stored TRANSPOSED per batch:
//   ewt[b][h][s] = e^{2*(enc@W1)[b,s,h]}     (s-contiguous for coalescing)
//   dwc[t_glob][h] = e^{2*(dec@W2)[t,h]}     (row-major)
// ---------------------------------------------------------------------------
__global__ __launch_bounds__(512)
void prep_kernel(const float* __restrict__ enc, const float* __restrict__ dec,
                 const float* __restrict__ W1, const float* __restrict__ W2,
                 const void* __restrict__ mask_raw,
                 float* __restrict__ ewt, float* __restrict__ dwc,
                 float* __restrict__ mask_f) {
    const int bx = blockIdx.x;
    const int tid = threadIdx.x;

    if (bx == GEMM_BLOCKS) {
        // ---- mask decode (layout auto-detect: int32 / byte / float) ----
        const unsigned int* w = (const unsigned int*)mask_raw;
        unsigned int gt1 = 0, flt = 0;
        {   // first 512 words (2048 B) safe under every candidate layout
            unsigned int v = w[tid];
            if (v == 0x3f800000u) flt = 1;
            else if (v > 1u) gt1 = 1;
        }
        __shared__ unsigned int s_gt1, s_flt;
        if (tid == 0) { s_gt1 = 0u; s_flt = 0u; }
        __syncthreads();
        if (gt1) atomicOr(&s_gt1, 1u);
        if (flt) atomicOr(&s_flt, 1u);
        __syncthreads();
        const int mode = s_flt ? 2 : (s_gt1 ? 1 : 0);
        for (int i = tid; i < kB * kTE; i += 512) {
            float val;
            if (mode == 2)      val = ((const float*)mask_raw)[i];
            else if (mode == 1) val = (float)(((const unsigned char*)mask_raw)[i]);
            else                val = (float)(((const int*)mask_raw)[i]);
            mask_f[i] = val;
        }
        return;
    }

    const bool is_enc = (bx < 256);
    const float* A; const float* W; int m0, n0;
    if (is_enc) { A = enc; W = W1; m0 = (bx >> 3) * 64; n0 = (bx & 7) * 64; }
    else { int b2 = bx - 256; A = dec; W = W2; m0 = (b2 >> 3) * 64; n0 = (b2 & 7) * 64; }

    __shared__ float As[2][32][68];   // [half][k][m]
    __shared__ float Bs[2][32][64];   // [half][k][n]

    const int half = tid >> 8;        // K-half owner
    const int lid  = tid & 255;
    const int kbase = half * 256;
    const int tx = lid & 15;
    const int ty = lid >> 4;

    float acc[4][4] = {};

    for (int k0 = 0; k0 < 256; k0 += 32) {
        const int kk0 = kbase + k0;
        #pragma unroll
        for (int p = 0; p < 2; ++p) {       // A: 64 rows x 32 k
            int i = lid + p * 256;
            int r = i >> 3, c4 = i & 7;
            float4 av = *(const float4*)&A[(size_t)(m0 + r) * kH + kk0 + c4 * 4];
            As[half][c4 * 4 + 0][r] = av.x;
            As[half][c4 * 4 + 1][r] = av.y;
            As[half][c4 * 4 + 2][r] = av.z;
            As[half][c4 * 4 + 3][r] = av.w;
        }
        #pragma unroll
        for (int p = 0; p < 2; ++p) {       // B: 32 k x 64 n
            int i = lid + p * 256;
            int kr = i >> 4, c4 = i & 15;
            *(float4*)&Bs[half][kr][c4 * 4] =
                *(const float4*)&W[(size_t)(kk0 + kr) * kH + n0 + c4 * 4];
        }
        __syncthreads();

        #pragma unroll
        for (int kk = 0; kk < 32; ++kk) {
            float4 a  = *(const float4*)&As[half][kk][ty * 4];
            float4 bq = *(const float4*)&Bs[half][kk][tx * 4];
            float av[4] = {a.x, a.y, a.z, a.w};
            float bv[4] = {bq.x, bq.y, bq.z, bq.w};
            #pragma unroll
            for (int i = 0; i < 4; ++i)
                #pragma unroll
                for (int j = 0; j < 4; ++j)
                    acc[i][j] = fmaf(av[i], bv[j], acc[i][j]);
        }
        __syncthreads();
    }

    // combine K-halves via LDS (reuse As as 64x65 scratch; 4160 <= 4352 floats)
    float* comb = &As[0][0][0];
    if (half == 1) {
        #pragma unroll
        for (int i = 0; i < 4; ++i)
            #pragma unroll
            for (int j = 0; j < 4; ++j)
                comb[(ty * 4 + i) * 65 + tx * 4 + j] = acc[i][j];
    }
    __syncthreads();
    if (half == 0) {
        #pragma unroll
        for (int i = 0; i < 4; ++i)
            #pragma unroll
            for (int j = 0; j < 4; ++j)
                acc[i][j] += comb[(ty * 4 + i) * 65 + tx * 4 + j];

        if (is_enc) {
            // store transposed: ewt[(b*kH + n) * kTE + s]
            #pragma unroll
            for (int i = 0; i < 4; ++i) {
                const int m = m0 + ty * 4 + i;
                const int bb = m >> 8, s = m & 255;
                #pragma unroll
                for (int j = 0; j < 4; ++j) {
                    float o = __builtin_amdgcn_exp2f(acc[i][j] * kTwoLog2e);
                    ewt[((size_t)bb * kH + n0 + tx * 4 + j) * kTE + s] = o;
                }
            }
        } else {
            #pragma unroll
            for (int i = 0; i < 4; ++i) {
                float4 o;
                o.x = __builtin_amdgcn_exp2f(acc[i][0] * kTwoLog2e);
                o.y = __builtin_amdgcn_exp2f(acc[i][1] * kTwoLog2e);
                o.z = __builtin_amdgcn_exp2f(acc[i][2] * kTwoLog2e);
                o.w = __builtin_amdgcn_exp2f(acc[i][3] * kTwoLog2e);
                *(float4*)&dwc[(size_t)(m0 + ty * 4 + i) * kH + n0 + tx * 4] = o;
            }
        }
    }
}

// ---------------------------------------------------------------------------
// Kernel 2 (fused): scores -> softmax -> context, one (b, 4-t tile) per block.
//   1024 threads: s = tid&255, hq = tid>>8 (h-quarter of 128).
//   tanh(ew+dw) = 1 - 2/(E*P+1); rcp-paired:
//     Vx/(A)+Vy/(B) = (Vx*B+Vy*A) * rcp(A*B)
//   score_t = SV - 2 * sum_h V_h / (E_h*P_{t,h} + 1)
// ---------------------------------------------------------------------------
__global__ __launch_bounds__(1024)
void fused_attn_kernel(const float* __restrict__ ewt, const float* __restrict__ dwc,
                       const float* __restrict__ enc, const float* __restrict__ V,
                       const float* __restrict__ mask_f,
                       float* __restrict__ ctx_out, float* __restrict__ attn_out) {
    const int bid = blockIdx.x;
    const int b   = bid & 7;            // XCD-pinned batch (round-robin dispatch)
    const int t0  = (bid >> 3) * TM;
    const int tid = threadIdx.x;
    const int s   = tid & 255;
    const int hq  = tid >> 8;           // 0..3 (128 h each)

    __shared__ float p_s[TM][kH];       // P rows (pre-exponentiated dw)
    __shared__ float v_s[kH];
    __shared__ float part[3][TM][kTE];  // h-quarter partial sums (hq 1..3)
    __shared__ float4 wgt4[kTE];        // softmax weights, t-major
    __shared__ float red_mx[4][TM], red_sm[4][TM];
    __shared__ float sv_red;

    // stage P (4 rows) and V
    if (tid < 512)
        ((float4*)&p_s[0][0])[tid] =
            ((const float4*)(dwc + (size_t)(b * kTD + t0) * kH))[tid];
    else if (tid < 640)
        ((float4*)v_s)[tid - 512] = ((const float4*)V)[tid - 512];
    __syncthreads();

    // SV = sum_h V_h (wave 0; consumed after the part-combine barrier)
    if (tid < 64) {
        float sv = 0.0f;
        #pragma unroll
        for (int k = 0; k < 8; ++k) sv += v_s[tid + k * 64];
        #pragma unroll
        for (int off = 1; off < 64; off <<= 1) sv += __shfl_xor(sv, off);
        if (tid == 0) sv_red = sv;
    }

    // ---- score phase over this thread's 128-h quarter ----
    const float*  ep = ewt + ((size_t)b * kH + hq * 128) * kTE + s;  // stride 256/h
    const float4* P0 = (const float4*)&p_s[0][hq * 128];
    const float4* P1 = (const float4*)&p_s[1][hq * 128];
    const float4* P2 = (const float4*)&p_s[2][hq * 128];
    const float4* P3 = (const float4*)&p_s[3][hq * 128];
    const float4* V4 = (const float4*)&v_s[hq * 128];

    float a0 = 0.0f, a1 = 0.0f, a2 = 0.0f, a3 = 0.0f;
    #pragma unroll 4
    for (int g = 0; g < 32; ++g) {
        const float* e = ep + (size_t)g * 4 * kTE;
        float e0 = e[0], e1 = e[kTE], e2 = e[2 * kTE], e3 = e[3 * kTE];
        float4 vv = V4[g];
        {   float4 q = P0[g];
            float A_ = fmaf(e0, q.x, 1.0f), B_ = fmaf(e1, q.y, 1.0f);
            float n1 = fmaf(vv.y, A_, vv.x * B_);
            a0 = fmaf(n1, __builtin_amdgcn_rcpf(A_ * B_), a0);
            float C_ = fmaf(e2, q.z, 1.0f), D_ = fmaf(e3, q.w, 1.0f);
            float n2 = fmaf(vv.w, C_, vv.z * D_);
            a0 = fmaf(n2, __builtin_amdgcn_rcpf(C_ * D_), a0); }
        {   float4 q = P1[g];
            float A_ = fmaf(e0, q.x, 1.0f), B_ = fmaf(e1, q.y, 1.0f);
            float n1 = fmaf(vv.y, A_, vv.x * B_);
            a1 = fmaf(n1, __builtin_amdgcn_rcpf(A_ * B_), a1);
            float C_ = fmaf(e2, q.z, 1.0f), D_ = fmaf(e3, q.w, 1.0f);
            float n2 = fmaf(vv.w, C_, vv.z * D_);
            a1 = fmaf(n2, __builtin_amdgcn_rcpf(C_ * D_), a1); }
        {   float4 q = P2[g];
            float A_ = fmaf(e0, q.x, 1.0f), B_ = fmaf(e1, q.y, 1.0f);
            float n1 = fmaf(vv.y, A_, vv.x * B_);
            a2 = fmaf(n1, __builtin_amdgcn_rcpf(A_ * B_), a2);
            float C_ = fmaf(e2, q.z, 1.0f), D_ = fmaf(e3, q.w, 1.0f);
            float n2 = fmaf(vv.w, C_, vv.z * D_);
            a2 = fmaf(n2, __builtin_amdgcn_rcpf(C_ * D_), a2); }
        {   float4 q = P3[g];
            float A_ = fmaf(e0, q.x, 1.0f), B_ = fmaf(e1, q.y, 1.0f);
            float n1 = fmaf(vv.y, A_, vv.x * B_);
            a3 = fmaf(n1, __builtin_amdgcn_rcpf(A_ * B_), a3);
            float C_ = fmaf(e2, q.z, 1.0f), D_ = fmaf(e3, q.w, 1.0f);
            float n2 = fmaf(vv.w, C_, vv.z * D_);
            a3 = fmaf(n2, __builtin_amdgcn_rcpf(C_ * D_), a3); }
    }

    if (hq > 0) {
        part[hq - 1][0][s] = a0; part[hq - 1][1][s] = a1;
        part[hq - 1][2][s] = a2; part[hq - 1][3][s] = a3;
    }
    __syncthreads();

    const bool active = (hq == 0);
    const int wv = s >> 6;
    float sc0, sc1, sc2, sc3;
    if (active) {
        const float sv = sv_red;
        const float pen = (1.0f - mask_f[b * kTE + s]) * -1e9f;
        sc0 = fmaf(-2.0f, ((a0 + part[0][0][s]) + (part[1][0][s] + part[2][0][s])), sv) + pen;
        sc1 = fmaf(-2.0f, ((a1 + part[0][1][s]) + (part[1][1][s] + part[2][1][s])), sv) + pen;
        sc2 = fmaf(-2.0f, ((a2 + part[0][2][s]) + (part[1][2][s] + part[2][2][s])), sv) + pen;
        sc3 = fmaf(-2.0f, ((a3 + part[0][3][s]) + (part[1][3][s] + part[2][3][s])), sv) + pen;
        float m0 = sc0, m1 = sc1, m2 = sc2, m3 = sc3;
        #pragma unroll
        for (int off = 1; off < 64; off <<= 1) {
            m0 = fmaxf(m0, __shfl_xor(m0, off));
            m1 = fmaxf(m1, __shfl_xor(m1, off));
            m2 = fmaxf(m2, __shfl_xor(m2, off));
            m3 = fmaxf(m3, __shfl_xor(m3, off));
        }
        if ((s & 63) == 0) {
            red_mx[wv][0] = m0; red_mx[wv][1] = m1;
            red_mx[wv][2] = m2; red_mx[wv][3] = m3;
        }
    }
    __syncthreads();

    float p0, p1, p2, p3;
    if (active) {
        float m0 = fmaxf(fmaxf(red_mx[0][0], red_mx[1][0]), fmaxf(red_mx[2][0], red_mx[3][0]));
        float m1 = fmaxf(fmaxf(red_mx[0][1], red_mx[1][1]), fmaxf(red_mx[2][1], red_mx[3][1]));
        float m2 = fmaxf(fmaxf(red_mx[0][2], red_mx[1][2]), fmaxf(red_mx[2][2], red_mx[3][2]));
        float m3 = fmaxf(fmaxf(red_mx[0][3], red_mx[1][3]), fmaxf(red_mx[2][3], red_mx[3][3]));
        p0 = __builtin_amdgcn_exp2f((sc0 - m0) * kLog2e);
        p1 = __builtin_amdgcn_exp2f((sc1 - m1) * kLog2e);
        p2 = __builtin_amdgcn_exp2f((sc2 - m2) * kLog2e);
        p3 = __builtin_amdgcn_exp2f((sc3 - m3) * kLog2e);
        float s0 = p0, s1 = p1, s2 = p2, s3 = p3;
        #pragma unroll
        for (int off = 1; off < 64; off <<= 1) {
            s0 += __shfl_xor(s0, off);
            s1 += __shfl_xor(s1, off);
            s2 += __shfl_xor(s2, off);
            s3 += __shfl_xor(s3, off);
        }
        if ((s & 63) == 0) {
            red_sm[wv][0] = s0; red_sm[wv][1] = s1;
            red_sm[wv][2] = s2; red_sm[wv][3] = s3;
        }
    }
    __syncthreads();

    if (active) {
        float s0 = (red_sm[0][0] + red_sm[1][0]) + (red_sm[2][0] + red_sm[3][0]);
        float s1 = (red_sm[0][1] + red_sm[1][1]) + (red_sm[2][1] + red_sm[3][1]);
        float s2 = (red_sm[0][2] + red_sm[1][2]) + (red_sm[2][2] + red_sm[3][2]);
        float s3 = (red_sm[0][3] + red_sm[1][3]) + (red_sm[2][3] + red_sm[3][3]);
        float4 w;
        w.x = p0 * __builtin_amdgcn_rcpf(s0);
        w.y = p1 * __builtin_amdgcn_rcpf(s1);
        w.z = p2 * __builtin_amdgcn_rcpf(s2);
        w.w = p3 * __builtin_amdgcn_rcpf(s3);
        wgt4[s] = w;
        float* ao = attn_out + (size_t)(b * kTD + t0) * kTE + s;
        ao[0]       = w.x;
        ao[kTE]     = w.y;
        ao[2 * kTE] = w.z;
        ao[3 * kTE] = w.w;
    }
    __syncthreads();

    // ---- context phase: tg = tid>>9 owns 2 of the 4 t's; h = tid&511 ----
    const int tg = tid >> 9;
    const int h  = tid & 511;
    const float* encb = enc + (size_t)b * kTE * kH + h;
    float c0 = 0.0f, c1 = 0.0f;
    #pragma unroll 4
    for (int ss = 0; ss < kTE; ++ss) {
        float e = encb[(size_t)ss * kH];
        float2 wp = ((const float2*)&wgt4[ss])[tg];
        c0 = fmaf(wp.x, e, c0);
        c1 = fmaf(wp.y, e, c1);
    }
    float* co = ctx_out + (size_t)(b * kTD + t0) * kH;
    co[(size_t)(tg * 2 + 0) * kH + h] = c0;
    co[(size_t)(tg * 2 + 1) * kH + h] = c1;
}

// ---------------------------------------------------------------------------
extern "C" void kernel_launch(void* const* d_in, const int* in_sizes, int n_in,
                              void* d_out, int out_size, void* d_ws, size_t ws_size,
                              hipStream_t stream) {
    const float* enc  = (const float*)d_in[0];   // [B, TE, H]
    const float* dec  = (const float*)d_in[1];   // [B, TD, H]
    const void*  mask = d_in[2];                 // [B, TE] bool
    const float* W1   = (const float*)d_in[3];
    const float* W2   = (const float*)d_in[4];
    const float* V    = (const float*)d_in[5];   // [H, 1]

    float* ctx_out  = (float*)d_out;                     // [B, TD, H]
    float* attn_out = (float*)d_out + kB * kTD * kH;     // [B, TD, TE]

    char* ws = (char*)d_ws;
    float* mask_f = (float*)ws;                                      // 2048 f
    float* ewt    = (float*)(ws + 8192);                             // E^T[b][h][s]
    float* dwc    = (float*)(ws + 8192 + (size_t)kB * kTE * kH * 4); // P[t][h]

    hipLaunchKernelGGL(prep_kernel, dim3(GEMM_BLOCKS + 1), dim3(512), 0, stream,
                       enc, dec, W1, W2, mask, ewt, dwc, mask_f);
    hipLaunchKernelGGL(fused_attn_kernel, dim3(kB * kTD / TM), dim3(1024), 0, stream,
                       ewt, dwc, enc, V, mask_f, ctx_out, attn_out);
}

// Round 4
// 57.770 us; speedup vs baseline: 2.6851x; 1.2404x over previous
//
#include <hip/hip_runtime.h>
#include <hip/hip_bf16.h>
#include <math.h>

// Problem constants
constexpr int kB  = 8;
constexpr int kTD = 128;
constexpr int kTE = 256;
constexpr int kH  = 512;

constexpr float kTwoLog2e = 2.8853900817779268f; // 2*log2(e)
constexpr float kLog2e    = 1.4426950408889634f;

constexpr int TM = 4;              // t-tile in fused kernel
constexpr int GEMM_BLOCKS = 384;   // 256 (enc) + 128 (dec)

// ---------------------------------------------------------------------------
// Kernel 1 (prep): both GEMMs (64x64 tile, 512 threads, K split in halves)
// with exp2 epilogue + mask decode.
//   enc result, PACKED-TRANSPOSED: ewt4[b][h>>2][s] = float4 of
//       e^{2*(enc@W1)[b,s,h..h+3]}        (s-contiguous float4s)
//   dec result, row-major: dwc[t_glob][h] = e^{2*(dec@W2)[t,h]}
// ---------------------------------------------------------------------------
__global__ __launch_bounds__(512)
void prep_kernel(const float* __restrict__ enc, const float* __restrict__ dec,
                 const float* __restrict__ W1, const float* __restrict__ W2,
                 const void* __restrict__ mask_raw,
                 float* __restrict__ ewt, float* __restrict__ dwc,
                 float* __restrict__ mask_f) {
    const int bx = blockIdx.x;
    const int tid = threadIdx.x;

    if (bx == GEMM_BLOCKS) {
        // ---- mask decode (layout auto-detect: int32 / byte / float) ----
        const unsigned int* w = (const unsigned int*)mask_raw;
        unsigned int gt1 = 0, flt = 0;
        {   // first 512 words (2048 B) safe under every candidate layout
            unsigned int v = w[tid];
            if (v == 0x3f800000u) flt = 1;
            else if (v > 1u) gt1 = 1;
        }
        __shared__ unsigned int s_gt1, s_flt;
        if (tid == 0) { s_gt1 = 0u; s_flt = 0u; }
        __syncthreads();
        if (gt1) atomicOr(&s_gt1, 1u);
        if (flt) atomicOr(&s_flt, 1u);
        __syncthreads();
        const int mode = s_flt ? 2 : (s_gt1 ? 1 : 0);
        for (int i = tid; i < kB * kTE; i += 512) {
            float val;
            if (mode == 2)      val = ((const float*)mask_raw)[i];
            else if (mode == 1) val = (float)(((const unsigned char*)mask_raw)[i]);
            else                val = (float)(((const int*)mask_raw)[i]);
            mask_f[i] = val;
        }
        return;
    }

    const bool is_enc = (bx < 256);
    const float* A; const float* W; int m0, n0;
    if (is_enc) { A = enc; W = W1; m0 = (bx >> 3) * 64; n0 = (bx & 7) * 64; }
    else { int b2 = bx - 256; A = dec; W = W2; m0 = (b2 >> 3) * 64; n0 = (b2 & 7) * 64; }

    __shared__ float As[2][32][68];   // [half][k][m]
    __shared__ float Bs[2][32][64];   // [half][k][n]

    const int half = tid >> 8;        // K-half owner
    const int lid  = tid & 255;
    const int kbase = half * 256;
    const int tx = lid & 15;
    const int ty = lid >> 4;

    float acc[4][4] = {};

    for (int k0 = 0; k0 < 256; k0 += 32) {
        const int kk0 = kbase + k0;
        #pragma unroll
        for (int p = 0; p < 2; ++p) {       // A: 64 rows x 32 k
            int i = lid + p * 256;
            int r = i >> 3, c4 = i & 7;
            float4 av = *(const float4*)&A[(size_t)(m0 + r) * kH + kk0 + c4 * 4];
            As[half][c4 * 4 + 0][r] = av.x;
            As[half][c4 * 4 + 1][r] = av.y;
            As[half][c4 * 4 + 2][r] = av.z;
            As[half][c4 * 4 + 3][r] = av.w;
        }
        #pragma unroll
        for (int p = 0; p < 2; ++p) {       // B: 32 k x 64 n
            int i = lid + p * 256;
            int kr = i >> 4, c4 = i & 15;
            *(float4*)&Bs[half][kr][c4 * 4] =
                *(const float4*)&W[(size_t)(kk0 + kr) * kH + n0 + c4 * 4];
        }
        __syncthreads();

        #pragma unroll
        for (int kk = 0; kk < 32; ++kk) {
            float4 a  = *(const float4*)&As[half][kk][ty * 4];
            float4 bq = *(const float4*)&Bs[half][kk][tx * 4];
            float av[4] = {a.x, a.y, a.z, a.w};
            float bv[4] = {bq.x, bq.y, bq.z, bq.w};
            #pragma unroll
            for (int i = 0; i < 4; ++i)
                #pragma unroll
                for (int j = 0; j < 4; ++j)
                    acc[i][j] = fmaf(av[i], bv[j], acc[i][j]);
        }
        __syncthreads();
    }

    // combine K-halves via LDS (reuse As as 64x65 scratch)
    float* comb = &As[0][0][0];
    if (half == 1) {
        #pragma unroll
        for (int i = 0; i < 4; ++i)
            #pragma unroll
            for (int j = 0; j < 4; ++j)
                comb[(ty * 4 + i) * 65 + tx * 4 + j] = acc[i][j];
    }
    __syncthreads();
    if (half == 0) {
        #pragma unroll
        for (int i = 0; i < 4; ++i)
            #pragma unroll
            for (int j = 0; j < 4; ++j)
                acc[i][j] += comb[(ty * 4 + i) * 65 + tx * 4 + j];

        if (is_enc) {
            // packed-transposed store: one float4 per output row quad
            #pragma unroll
            for (int i = 0; i < 4; ++i) {
                const int m = m0 + ty * 4 + i;          // = b*256 + s
                const int bb = m >> 8, sE = m & 255;
                float4 o;
                o.x = __builtin_amdgcn_exp2f(acc[i][0] * kTwoLog2e);
                o.y = __builtin_amdgcn_exp2f(acc[i][1] * kTwoLog2e);
                o.z = __builtin_amdgcn_exp2f(acc[i][2] * kTwoLog2e);
                o.w = __builtin_amdgcn_exp2f(acc[i][3] * kTwoLog2e);
                *(float4*)&ewt[(((size_t)bb * 128 + (n0 >> 2) + tx) * 256 + sE) * 4] = o;
            }
        } else {
            #pragma unroll
            for (int i = 0; i < 4; ++i) {
                float4 o;
                o.x = __builtin_amdgcn_exp2f(acc[i][0] * kTwoLog2e);
                o.y = __builtin_amdgcn_exp2f(acc[i][1] * kTwoLog2e);
                o.z = __builtin_amdgcn_exp2f(acc[i][2] * kTwoLog2e);
                o.w = __builtin_amdgcn_exp2f(acc[i][3] * kTwoLog2e);
                *(float4*)&dwc[(size_t)(m0 + ty * 4 + i) * kH + n0 + tx * 4] = o;
            }
        }
    }
}

// ---------------------------------------------------------------------------
// Kernel 2 (fused): scores -> softmax -> context, one (b, 4-t tile) per block.
//   1024 threads: s = tid&255, hq = tid>>8 (h-quarter of 128).
//   tanh(ew+dw) = 1 - 2/(E*P+1); E packed float4 (1 vmem load / 4 h);
//   P,V wave-uniform -> SGPR via readfirstlane'd addresses (s_load).
//   4-way rcp pairing: sum V_i/D_i = [(V1*B+V2*A)*CD+(V3*D+V4*C)*AB]*rcp(AB*CD)
//   Global constant sum_h V_h cancels in softmax -> dropped.
// ---------------------------------------------------------------------------
__global__ __launch_bounds__(1024)
void fused_attn_kernel(const float* __restrict__ ewt, const float* __restrict__ dwc,
                       const float* __restrict__ enc, const float* __restrict__ V,
                       const float* __restrict__ mask_f,
                       float* __restrict__ ctx_out, float* __restrict__ attn_out) {
    const int bid = blockIdx.x;
    const int b   = bid & 7;            // XCD-pinned batch
    const int t0  = (bid >> 3) * TM;
    const int tid = threadIdx.x;
    const int s   = tid & 255;
    const int hq  = tid >> 8;           // 0..3 (128 h each)
    const int hqu = __builtin_amdgcn_readfirstlane(hq);  // wave-uniform

    __shared__ float part[3 * TM * kTE];   // score partials; reused as ctx partials
    __shared__ float4 wgt4[kTE];           // softmax weights, t-major
    __shared__ float red_mx[4][TM], red_sm[4][TM];

    // ---- score phase over this thread's 128-h quarter ----
    const float4* E4 = (const float4*)ewt + ((size_t)(b * 128 + hqu * 32) * 256 + s);
    const float4* Pb = (const float4*)(dwc + (size_t)(b * kTD + t0) * kH) + hqu * 32;
    const float4* V4 = (const float4*)V + hqu * 32;

    float a0 = 0.0f, a1 = 0.0f, a2 = 0.0f, a3 = 0.0f;
    #pragma unroll 2
    for (int g = 0; g < 32; ++g) {
        float4 e  = E4[(size_t)g * 256];
        float4 vv = V4[g];
        {   float4 q = Pb[g];
            float A_ = fmaf(e.x, q.x, 1.0f), B_ = fmaf(e.y, q.y, 1.0f);
            float C_ = fmaf(e.z, q.z, 1.0f), D_ = fmaf(e.w, q.w, 1.0f);
            float t1 = fmaf(vv.y, A_, vv.x * B_);
            float t2 = fmaf(vv.w, C_, vv.z * D_);
            float AB = A_ * B_, CD = C_ * D_;
            float num = fmaf(t2, AB, t1 * CD);
            a0 = fmaf(num, __builtin_amdgcn_rcpf(AB * CD), a0); }
        {   float4 q = Pb[128 + g];
            float A_ = fmaf(e.x, q.x, 1.0f), B_ = fmaf(e.y, q.y, 1.0f);
            float C_ = fmaf(e.z, q.z, 1.0f), D_ = fmaf(e.w, q.w, 1.0f);
            float t1 = fmaf(vv.y, A_, vv.x * B_);
            float t2 = fmaf(vv.w, C_, vv.z * D_);
            float AB = A_ * B_, CD = C_ * D_;
            float num = fmaf(t2, AB, t1 * CD);
            a1 = fmaf(num, __builtin_amdgcn_rcpf(AB * CD), a1); }
        {   float4 q = Pb[256 + g];
            float A_ = fmaf(e.x, q.x, 1.0f), B_ = fmaf(e.y, q.y, 1.0f);
            float C_ = fmaf(e.z, q.z, 1.0f), D_ = fmaf(e.w, q.w, 1.0f);
            float t1 = fmaf(vv.y, A_, vv.x * B_);
            float t2 = fmaf(vv.w, C_, vv.z * D_);
            float AB = A_ * B_, CD = C_ * D_;
            float num = fmaf(t2, AB, t1 * CD);
            a2 = fmaf(num, __builtin_amdgcn_rcpf(AB * CD), a2); }
        {   float4 q = Pb[384 + g];
            float A_ = fmaf(e.x, q.x, 1.0f), B_ = fmaf(e.y, q.y, 1.0f);
            float C_ = fmaf(e.z, q.z, 1.0f), D_ = fmaf(e.w, q.w, 1.0f);
            float t1 = fmaf(vv.y, A_, vv.x * B_);
            float t2 = fmaf(vv.w, C_, vv.z * D_);
            float AB = A_ * B_, CD = C_ * D_;
            float num = fmaf(t2, AB, t1 * CD);
            a3 = fmaf(num, __builtin_amdgcn_rcpf(AB * CD), a3); }
    }

    if (hq > 0) {
        float* pp = &part[(hq - 1) * TM * kTE];
        pp[0 * kTE + s] = a0; pp[1 * kTE + s] = a1;
        pp[2 * kTE + s] = a2; pp[3 * kTE + s] = a3;
    }
    __syncthreads();

    const bool active = (hq == 0);
    const int wv = s >> 6;
    float sc0, sc1, sc2, sc3;
    if (active) {
        const float pen = (1.0f - mask_f[b * kTE + s]) * -1e9f;
        // score = -2 * sum (SV constant dropped; softmax shift-invariant)
        sc0 = -2.0f * ((a0 + part[0 * TM * kTE + 0 * kTE + s]) +
                       (part[1 * TM * kTE + 0 * kTE + s] + part[2 * TM * kTE + 0 * kTE + s])) + pen;
        sc1 = -2.0f * ((a1 + part[0 * TM * kTE + 1 * kTE + s]) +
                       (part[1 * TM * kTE + 1 * kTE + s] + part[2 * TM * kTE + 1 * kTE + s])) + pen;
        sc2 = -2.0f * ((a2 + part[0 * TM * kTE + 2 * kTE + s]) +
                       (part[1 * TM * kTE + 2 * kTE + s] + part[2 * TM * kTE + 2 * kTE + s])) + pen;
        sc3 = -2.0f * ((a3 + part[0 * TM * kTE + 3 * kTE + s]) +
                       (part[1 * TM * kTE + 3 * kTE + s] + part[2 * TM * kTE + 3 * kTE + s])) + pen;
        float m0 = sc0, m1 = sc1, m2 = sc2, m3 = sc3;
        #pragma unroll
        for (int off = 1; off < 64; off <<= 1) {
            m0 = fmaxf(m0, __shfl_xor(m0, off));
            m1 = fmaxf(m1, __shfl_xor(m1, off));
            m2 = fmaxf(m2, __shfl_xor(m2, off));
            m3 = fmaxf(m3, __shfl_xor(m3, off));
        }
        if ((s & 63) == 0) {
            red_mx[wv][0] = m0; red_mx[wv][1] = m1;
            red_mx[wv][2] = m2; red_mx[wv][3] = m3;
        }
    }
    __syncthreads();

    float p0, p1, p2, p3;
    if (active) {
        float m0 = fmaxf(fmaxf(red_mx[0][0], red_mx[1][0]), fmaxf(red_mx[2][0], red_mx[3][0]));
        float m1 = fmaxf(fmaxf(red_mx[0][1], red_mx[1][1]), fmaxf(red_mx[2][1], red_mx[3][1]));
        float m2 = fmaxf(fmaxf(red_mx[0][2], red_mx[1][2]), fmaxf(red_mx[2][2], red_mx[3][2]));
        float m3 = fmaxf(fmaxf(red_mx[0][3], red_mx[1][3]), fmaxf(red_mx[2][3], red_mx[3][3]));
        p0 = __builtin_amdgcn_exp2f((sc0 - m0) * kLog2e);
        p1 = __builtin_amdgcn_exp2f((sc1 - m1) * kLog2e);
        p2 = __builtin_amdgcn_exp2f((sc2 - m2) * kLog2e);
        p3 = __builtin_amdgcn_exp2f((sc3 - m3) * kLog2e);
        float s0 = p0, s1 = p1, s2 = p2, s3 = p3;
        #pragma unroll
        for (int off = 1; off < 64; off <<= 1) {
            s0 += __shfl_xor(s0, off);
            s1 += __shfl_xor(s1, off);
            s2 += __shfl_xor(s2, off);
            s3 += __shfl_xor(s3, off);
        }
        if ((s & 63) == 0) {
            red_sm[wv][0] = s0; red_sm[wv][1] = s1;
            red_sm[wv][2] = s2; red_sm[wv][3] = s3;
        }
    }
    __syncthreads();

    if (active) {
        float s0 = (red_sm[0][0] + red_sm[1][0]) + (red_sm[2][0] + red_sm[3][0]);
        float s1 = (red_sm[0][1] + red_sm[1][1]) + (red_sm[2][1] + red_sm[3][1]);
        float s2 = (red_sm[0][2] + red_sm[1][2]) + (red_sm[2][2] + red_sm[3][2]);
        float s3 = (red_sm[0][3] + red_sm[1][3]) + (red_sm[2][3] + red_sm[3][3]);
        float4 w;
        w.x = p0 * __builtin_amdgcn_rcpf(s0);
        w.y = p1 * __builtin_amdgcn_rcpf(s1);
        w.z = p2 * __builtin_amdgcn_rcpf(s2);
        w.w = p3 * __builtin_amdgcn_rcpf(s3);
        wgt4[s] = w;
        float* ao = attn_out + (size_t)(b * kTD + t0) * kTE + s;
        ao[0]       = w.x;
        ao[kTE]     = w.y;
        ao[2 * kTE] = w.z;
        ao[3 * kTE] = w.w;
    }
    __syncthreads();

    // ---- context phase: h = tid&511, sh = tid>>9 splits s-range (no
    //      redundant enc reads); LDS combine of the two halves ----
    const int sh = tid >> 9;
    const int h  = tid & 511;
    const float* encb = enc + (size_t)b * kTE * kH + (size_t)sh * 128 * kH + h;
    float c0 = 0.0f, c1 = 0.0f, c2 = 0.0f, c3 = 0.0f;
    #pragma unroll 4
    for (int ss = 0; ss < 128; ++ss) {
        float e = encb[(size_t)ss * kH];
        float4 w = wgt4[sh * 128 + ss];
        c0 = fmaf(w.x, e, c0);
        c1 = fmaf(w.y, e, c1);
        c2 = fmaf(w.z, e, c2);
        c3 = fmaf(w.w, e, c3);
    }
    float* pctx = part;                 // reuse (done with score partials)
    if (sh == 1) {
        pctx[0 * 512 + h] = c0; pctx[1 * 512 + h] = c1;
        pctx[2 * 512 + h] = c2; pctx[3 * 512 + h] = c3;
    }
    __syncthreads();
    if (sh == 0) {
        float* co = ctx_out + (size_t)(b * kTD + t0) * kH + h;
        co[0]       = c0 + pctx[0 * 512 + h];
        co[kH]      = c1 + pctx[1 * 512 + h];
        co[2 * kH]  = c2 + pctx[2 * 512 + h];
        co[3 * kH]  = c3 + pctx[3 * 512 + h];
    }
}

// ---------------------------------------------------------------------------
extern "C" void kernel_launch(void* const* d_in, const int* in_sizes, int n_in,
                              void* d_out, int out_size, void* d_ws, size_t ws_size,
                              hipStream_t stream) {
    const float* enc  = (const float*)d_in[0];   // [B, TE, H]
    const float* dec  = (const float*)d_in[1];   // [B, TD, H]
    const void*  mask = d_in[2];                 // [B, TE] bool
    const float* W1   = (const float*)d_in[3];
    const float* W2   = (const float*)d_in[4];
    const float* V    = (const float*)d_in[5];   // [H, 1]

    float* ctx_out  = (float*)d_out;                     // [B, TD, H]
    float* attn_out = (float*)d_out + kB * kTD * kH;     // [B, TD, TE]

    char* ws = (char*)d_ws;
    float* mask_f = (float*)ws;                                      // 2048 f
    float* ewt    = (float*)(ws + 8192);                             // E^T packed [b][h/4][s][4]
    float* dwc    = (float*)(ws + 8192 + (size_t)kB * kTE * kH * 4); // P[t][h]

    hipLaunchKernelGGL(prep_kernel, dim3(GEMM_BLOCKS + 1), dim3(512), 0, stream,
                       enc, dec, W1, W2, mask, ewt, dwc, mask_f);
    hipLaunchKernelGGL(fused_attn_kernel, dim3(kB * kTD / TM), dim3(1024), 0, stream,
                       ewt, dwc, enc, V, mask_f, ctx_out, attn_out);
}

// Round 5
// 46.819 us; speedup vs baseline: 3.3132x; 1.2339x over previous
//
#include <hip/hip_runtime.h>
#include <hip/hip_bf16.h>
#include <math.h>

// Problem constants
constexpr int kB  = 8;
constexpr int kTD = 128;
constexpr int kTE = 256;
constexpr int kH  = 512;

constexpr float kTwoLog2e = 2.8853900817779268f; // 2*log2(e)
constexpr float kLog2e    = 1.4426950408889634f;

constexpr int TM = 4;              // t-tile in fused kernel
constexpr int GEMM_BLOCKS = 384;   // 48 m-tiles (32 enc + 16 dec) x 8 n-tiles

typedef __attribute__((ext_vector_type(8)))  short short8;   // 8 bf16 (4 VGPRs)
typedef __attribute__((ext_vector_type(16))) float f32x16;   // 32x32 acc

// round-to-nearest-even f32 -> bf16 (bit manip; no NaN inputs here)
__device__ __forceinline__ unsigned short f2bf(float x) {
    unsigned int u = __float_as_uint(x);
    return (unsigned short)((u + 0x7fffu + ((u >> 16) & 1u)) >> 16);
}
__device__ __forceinline__ float bf2f(unsigned short h) {
    return __uint_as_float(((unsigned int)h) << 16);
}

// ---------------------------------------------------------------------------
// Kernel 1 (prep): both GEMMs via split-bf16 MFMA (Ahi*Whi + Ahi*Wlo + Alo*Whi)
// 64x64 tile per 256-thread block (4 waves, 2x2 of 32x32), BK=32.
// Epilogue: C -> exp2(2*log2e*C).
//   enc rows (m < 2048): packed-transposed store ewt[b][h>>2][s][h&3]
//   dec rows (m >= 2048): row-major dwc[t][h]
// ---------------------------------------------------------------------------
__global__ __launch_bounds__(256)
void prep_kernel(const float* __restrict__ enc, const float* __restrict__ dec,
                 const float* __restrict__ W1, const float* __restrict__ W2,
                 const void* __restrict__ mask_raw,
                 float* __restrict__ ewt, float* __restrict__ dwc,
                 float* __restrict__ mask_f) {
    const int bx = blockIdx.x;
    const int tid = threadIdx.x;

    if (bx == GEMM_BLOCKS) {
        // ---- mask decode (layout auto-detect: int32 / byte / float) ----
        const unsigned int* w = (const unsigned int*)mask_raw;
        unsigned int gt1 = 0, flt = 0;
        for (int i = tid; i < 512; i += 256) {      // first 2048B safe everywhere
            unsigned int v = w[i];
            if (v == 0x3f800000u) flt = 1;
            else if (v > 1u) gt1 = 1;
        }
        __shared__ unsigned int s_gt1, s_flt;
        if (tid == 0) { s_gt1 = 0u; s_flt = 0u; }
        __syncthreads();
        if (gt1) atomicOr(&s_gt1, 1u);
        if (flt) atomicOr(&s_flt, 1u);
        __syncthreads();
        const int mode = s_flt ? 2 : (s_gt1 ? 1 : 0);
        for (int i = tid; i < kB * kTE; i += 256) {
            float val;
            if (mode == 2)      val = ((const float*)mask_raw)[i];
            else if (mode == 1) val = (float)(((const unsigned char*)mask_raw)[i]);
            else                val = (float)(((const int*)mask_raw)[i]);
            mask_f[i] = val;
        }
        return;
    }

    const int mt = bx >> 3;            // 0..47 m-tile
    const int nt = bx & 7;             // 0..7  n-tile
    const bool is_enc = (mt < 32);
    const int m0 = mt * 64;            // global row (enc rows 0..2047, dec 2048..)
    const int n0 = nt * 64;
    const float* Abase = is_enc ? (enc + (size_t)m0 * kH)
                                : (dec + (size_t)(m0 - 2048) * kH);
    const float* W = is_enc ? W1 : W2;

    // LDS: bf16 hi/lo tiles (pitch 40 ushorts = 80B, 16B aligned, low-conflict)
    __shared__ __align__(16) unsigned short Ahi[64][40], Alo[64][40];
    __shared__ __align__(16) unsigned short Bhi[64][40], Blo[64][40];
    __shared__ float Ws[32][68];       // fp32 W-tile for in-LDS transpose

    const int lane = tid & 63;
    const int wv   = tid >> 6;         // 4 waves
    const int wr   = wv >> 1, wc = wv & 1;
    const int col  = lane & 31, hi5 = lane >> 5;

    // staging roles
    const int ar  = tid >> 2;          // A: row 0..63
    const int akc = (tid & 3) * 8;     // A: k-chunk of 8
    const int wkr = tid >> 3;          // W pass1: k-row 0..31
    const int wnc = (tid & 7) * 8;     // W pass1: n-chunk of 8
    const int pn  = tid & 63;          // W pass2: n 0..63
    const int pkc = (tid >> 6) * 8;    // W pass2: k-chunk of 8

    f32x16 acc = {};

    // preload step 0
    float4 a0p = *(const float4*)&Abase[(size_t)ar * kH + akc];
    float4 a1p = *(const float4*)&Abase[(size_t)ar * kH + akc + 4];
    float4 w0p = *(const float4*)&W[(size_t)wkr * kH + n0 + wnc];
    float4 w1p = *(const float4*)&W[(size_t)wkr * kH + n0 + wnc + 4];

    for (int step = 0; step < 16; ++step) {
        // ---- stage W fp32 (pass1) + A hi/lo ----
        *(float4*)&Ws[wkr][wnc]     = w0p;
        *(float4*)&Ws[wkr][wnc + 4] = w1p;
        {
            uint4 H, L;
            float f[8] = {a0p.x, a0p.y, a0p.z, a0p.w, a1p.x, a1p.y, a1p.z, a1p.w};
            unsigned short hs[8], ls[8];
            #pragma unroll
            for (int j = 0; j < 8; ++j) {
                hs[j] = f2bf(f[j]);
                ls[j] = f2bf(f[j] - bf2f(hs[j]));
            }
            H.x = hs[0] | (hs[1] << 16); H.y = hs[2] | (hs[3] << 16);
            H.z = hs[4] | (hs[5] << 16); H.w = hs[6] | (hs[7] << 16);
            L.x = ls[0] | (ls[1] << 16); L.y = ls[2] | (ls[3] << 16);
            L.z = ls[4] | (ls[5] << 16); L.w = ls[6] | (ls[7] << 16);
            *(uint4*)&Ahi[ar][akc] = H;
            *(uint4*)&Alo[ar][akc] = L;
        }
        __syncthreads();

        // ---- W pass2: transpose-read columns, split, store K-major ----
        {
            uint4 H, L;
            unsigned short hs[8], ls[8];
            #pragma unroll
            for (int j = 0; j < 8; ++j) {
                float x = Ws[pkc + j][pn];
                hs[j] = f2bf(x);
                ls[j] = f2bf(x - bf2f(hs[j]));
            }
            H.x = hs[0] | (hs[1] << 16); H.y = hs[2] | (hs[3] << 16);
            H.z = hs[4] | (hs[5] << 16); H.w = hs[6] | (hs[7] << 16);
            L.x = ls[0] | (ls[1] << 16); L.y = ls[2] | (ls[3] << 16);
            L.z = ls[4] | (ls[5] << 16); L.w = ls[6] | (ls[7] << 16);
            *(uint4*)&Bhi[pn][pkc] = H;
            *(uint4*)&Blo[pn][pkc] = L;
        }

        // prefetch next step's globals (land during MFMA phase)
        if (step < 15) {
            const int k1 = (step + 1) * 32;
            a0p = *(const float4*)&Abase[(size_t)ar * kH + k1 + akc];
            a1p = *(const float4*)&Abase[(size_t)ar * kH + k1 + akc + 4];
            w0p = *(const float4*)&W[(size_t)(k1 + wkr) * kH + n0 + wnc];
            w1p = *(const float4*)&W[(size_t)(k1 + wkr) * kH + n0 + wnc + 4];
        }
        __syncthreads();

        // ---- fragments + MFMA: 2 k-chunks x 3 split-products ----
        #pragma unroll
        for (int kc = 0; kc < 32; kc += 16) {
            const int ka = kc + hi5 * 8;
            short8 ah = *(const short8*)&Ahi[wr * 32 + col][ka];
            short8 al = *(const short8*)&Alo[wr * 32 + col][ka];
            short8 bh = *(const short8*)&Bhi[wc * 32 + col][ka];
            short8 bl = *(const short8*)&Blo[wc * 32 + col][ka];
            acc = __builtin_amdgcn_mfma_f32_32x32x16_bf16(ah, bh, acc, 0, 0, 0);
            acc = __builtin_amdgcn_mfma_f32_32x32x16_bf16(ah, bl, acc, 0, 0, 0);
            acc = __builtin_amdgcn_mfma_f32_32x32x16_bf16(al, bh, acc, 0, 0, 0);
        }
        __syncthreads();
    }

    // ---- epilogue: exp2 + store ----
    const int h = n0 + wc * 32 + col;
    if (is_enc) {
        #pragma unroll
        for (int reg = 0; reg < 16; ++reg) {
            const int row = (reg & 3) + 8 * (reg >> 2) + 4 * hi5;
            const int gm = m0 + wr * 32 + row;            // = b*256 + s
            const int bb = gm >> 8, sE = gm & 255;
            float val = __builtin_amdgcn_exp2f(acc[reg] * kTwoLog2e);
            ewt[(((size_t)bb * 128 + (h >> 2)) * 256 + sE) * 4 + (h & 3)] = val;
        }
    } else {
        #pragma unroll
        for (int reg = 0; reg < 16; ++reg) {
            const int row = (reg & 3) + 8 * (reg >> 2) + 4 * hi5;
            const int dm = (m0 - 2048) + wr * 32 + row;   // = b*128 + t
            float val = __builtin_amdgcn_exp2f(acc[reg] * kTwoLog2e);
            dwc[(size_t)dm * kH + h] = val;
        }
    }
}

// ---------------------------------------------------------------------------
// Kernel 2 (fused): scores -> softmax -> context, one (b, 4-t tile) per block.
//   1024 threads: s = tid&255, hq = tid>>8 (h-quarter of 128).
//   tanh(ew+dw) = 1 - 2/(E*P+1); E packed float4 (1 vmem load / 4 h);
//   P,V wave-uniform -> SGPR. 4-way rcp pairing. SV constant cancels.
// ---------------------------------------------------------------------------
__global__ __launch_bounds__(1024)
void fused_attn_kernel(const float* __restrict__ ewt, const float* __restrict__ dwc,
                       const float* __restrict__ enc, const float* __restrict__ V,
                       const float* __restrict__ mask_f,
                       float* __restrict__ ctx_out, float* __restrict__ attn_out) {
    const int bid = blockIdx.x;
    const int b   = bid & 7;            // XCD-pinned batch
    const int t0  = (bid >> 3) * TM;
    const int tid = threadIdx.x;
    const int s   = tid & 255;
    const int hq  = tid >> 8;           // 0..3 (128 h each)
    const int hqu = __builtin_amdgcn_readfirstlane(hq);  // wave-uniform

    __shared__ float part[3 * TM * kTE];   // score partials; reused as ctx partials
    __shared__ float4 wgt4[kTE];           // softmax weights, t-major
    __shared__ float red_mx[4][TM], red_sm[4][TM];

    // ---- score phase over this thread's 128-h quarter ----
    const float4* E4 = (const float4*)ewt + ((size_t)(b * 128 + hqu * 32) * 256 + s);
    const float4* Pb = (const float4*)(dwc + (size_t)(b * kTD + t0) * kH) + hqu * 32;
    const float4* V4 = (const float4*)V + hqu * 32;

    float a0 = 0.0f, a1 = 0.0f, a2 = 0.0f, a3 = 0.0f;
    #pragma unroll 2
    for (int g = 0; g < 32; ++g) {
        float4 e  = E4[(size_t)g * 256];
        float4 vv = V4[g];
        {   float4 q = Pb[g];
            float A_ = fmaf(e.x, q.x, 1.0f), B_ = fmaf(e.y, q.y, 1.0f);
            float C_ = fmaf(e.z, q.z, 1.0f), D_ = fmaf(e.w, q.w, 1.0f);
            float t1 = fmaf(vv.y, A_, vv.x * B_);
            float t2 = fmaf(vv.w, C_, vv.z * D_);
            float AB = A_ * B_, CD = C_ * D_;
            float num = fmaf(t2, AB, t1 * CD);
            a0 = fmaf(num, __builtin_amdgcn_rcpf(AB * CD), a0); }
        {   float4 q = Pb[128 + g];
            float A_ = fmaf(e.x, q.x, 1.0f), B_ = fmaf(e.y, q.y, 1.0f);
            float C_ = fmaf(e.z, q.z, 1.0f), D_ = fmaf(e.w, q.w, 1.0f);
            float t1 = fmaf(vv.y, A_, vv.x * B_);
            float t2 = fmaf(vv.w, C_, vv.z * D_);
            float AB = A_ * B_, CD = C_ * D_;
            float num = fmaf(t2, AB, t1 * CD);
            a1 = fmaf(num, __builtin_amdgcn_rcpf(AB * CD), a1); }
        {   float4 q = Pb[256 + g];
            float A_ = fmaf(e.x, q.x, 1.0f), B_ = fmaf(e.y, q.y, 1.0f);
            float C_ = fmaf(e.z, q.z, 1.0f), D_ = fmaf(e.w, q.w, 1.0f);
            float t1 = fmaf(vv.y, A_, vv.x * B_);
            float t2 = fmaf(vv.w, C_, vv.z * D_);
            float AB = A_ * B_, CD = C_ * D_;
            float num = fmaf(t2, AB, t1 * CD);
            a2 = fmaf(num, __builtin_amdgcn_rcpf(AB * CD), a2); }
        {   float4 q = Pb[384 + g];
            float A_ = fmaf(e.x, q.x, 1.0f), B_ = fmaf(e.y, q.y, 1.0f);
            float C_ = fmaf(e.z, q.z, 1.0f), D_ = fmaf(e.w, q.w, 1.0f);
            float t1 = fmaf(vv.y, A_, vv.x * B_);
            float t2 = fmaf(vv.w, C_, vv.z * D_);
            float AB = A_ * B_, CD = C_ * D_;
            float num = fmaf(t2, AB, t1 * CD);
            a3 = fmaf(num, __builtin_amdgcn_rcpf(AB * CD), a3); }
    }

    if (hq > 0) {
        float* pp = &part[(hq - 1) * TM * kTE];
        pp[0 * kTE + s] = a0; pp[1 * kTE + s] = a1;
        pp[2 * kTE + s] = a2; pp[3 * kTE + s] = a3;
    }
    __syncthreads();

    const bool active = (hq == 0);
    const int wv = s >> 6;
    float sc0, sc1, sc2, sc3;
    if (active) {
        const float pen = (1.0f - mask_f[b * kTE + s]) * -1e9f;
        sc0 = -2.0f * ((a0 + part[0 * TM * kTE + 0 * kTE + s]) +
                       (part[1 * TM * kTE + 0 * kTE + s] + part[2 * TM * kTE + 0 * kTE + s])) + pen;
        sc1 = -2.0f * ((a1 + part[0 * TM * kTE + 1 * kTE + s]) +
                       (part[1 * TM * kTE + 1 * kTE + s] + part[2 * TM * kTE + 1 * kTE + s])) + pen;
        sc2 = -2.0f * ((a2 + part[0 * TM * kTE + 2 * kTE + s]) +
                       (part[1 * TM * kTE + 2 * kTE + s] + part[2 * TM * kTE + 2 * kTE + s])) + pen;
        sc3 = -2.0f * ((a3 + part[0 * TM * kTE + 3 * kTE + s]) +
                       (part[1 * TM * kTE + 3 * kTE + s] + part[2 * TM * kTE + 3 * kTE + s])) + pen;
        float m0 = sc0, m1 = sc1, m2 = sc2, m3 = sc3;
        #pragma unroll
        for (int off = 1; off < 64; off <<= 1) {
            m0 = fmaxf(m0, __shfl_xor(m0, off));
            m1 = fmaxf(m1, __shfl_xor(m1, off));
            m2 = fmaxf(m2, __shfl_xor(m2, off));
            m3 = fmaxf(m3, __shfl_xor(m3, off));
        }
        if ((s & 63) == 0) {
            red_mx[wv][0] = m0; red_mx[wv][1] = m1;
            red_mx[wv][2] = m2; red_mx[wv][3] = m3;
        }
    }
    __syncthreads();

    float p0, p1, p2, p3;
    if (active) {
        float m0 = fmaxf(fmaxf(red_mx[0][0], red_mx[1][0]), fmaxf(red_mx[2][0], red_mx[3][0]));
        float m1 = fmaxf(fmaxf(red_mx[0][1], red_mx[1][1]), fmaxf(red_mx[2][1], red_mx[3][1]));
        float m2 = fmaxf(fmaxf(red_mx[0][2], red_mx[1][2]), fmaxf(red_mx[2][2], red_mx[3][2]));
        float m3 = fmaxf(fmaxf(red_mx[0][3], red_mx[1][3]), fmaxf(red_mx[2][3], red_mx[3][3]));
        p0 = __builtin_amdgcn_exp2f((sc0 - m0) * kLog2e);
        p1 = __builtin_amdgcn_exp2f((sc1 - m1) * kLog2e);
        p2 = __builtin_amdgcn_exp2f((sc2 - m2) * kLog2e);
        p3 = __builtin_amdgcn_exp2f((sc3 - m3) * kLog2e);
        float s0 = p0, s1 = p1, s2 = p2, s3 = p3;
        #pragma unroll
        for (int off = 1; off < 64; off <<= 1) {
            s0 += __shfl_xor(s0, off);
            s1 += __shfl_xor(s1, off);
            s2 += __shfl_xor(s2, off);
            s3 += __shfl_xor(s3, off);
        }
        if ((s & 63) == 0) {
            red_sm[wv][0] = s0; red_sm[wv][1] = s1;
            red_sm[wv][2] = s2; red_sm[wv][3] = s3;
        }
    }
    __syncthreads();

    if (active) {
        float s0 = (red_sm[0][0] + red_sm[1][0]) + (red_sm[2][0] + red_sm[3][0]);
        float s1 = (red_sm[0][1] + red_sm[1][1]) + (red_sm[2][1] + red_sm[3][1]);
        float s2 = (red_sm[0][2] + red_sm[1][2]) + (red_sm[2][2] + red_sm[3][2]);
        float s3 = (red_sm[0][3] + red_sm[1][3]) + (red_sm[2][3] + red_sm[3][3]);
        float4 w;
        w.x = p0 * __builtin_amdgcn_rcpf(s0);
        w.y = p1 * __builtin_amdgcn_rcpf(s1);
        w.z = p2 * __builtin_amdgcn_rcpf(s2);
        w.w = p3 * __builtin_amdgcn_rcpf(s3);
        wgt4[s] = w;
        float* ao = attn_out + (size_t)(b * kTD + t0) * kTE + s;
        ao[0]       = w.x;
        ao[kTE]     = w.y;
        ao[2 * kTE] = w.z;
        ao[3 * kTE] = w.w;
    }
    __syncthreads();

    // ---- context phase: h = tid&511, sh = tid>>9 splits s-range; LDS combine ----
    const int sh = tid >> 9;
    const int h  = tid & 511;
    const float* encb = enc + (size_t)b * kTE * kH + (size_t)sh * 128 * kH + h;
    float c0 = 0.0f, c1 = 0.0f, c2 = 0.0f, c3 = 0.0f;
    #pragma unroll 4
    for (int ss = 0; ss < 128; ++ss) {
        float e = encb[(size_t)ss * kH];
        float4 w = wgt4[sh * 128 + ss];
        c0 = fmaf(w.x, e, c0);
        c1 = fmaf(w.y, e, c1);
        c2 = fmaf(w.z, e, c2);
        c3 = fmaf(w.w, e, c3);
    }
    float* pctx = part;                 // reuse (done with score partials)
    if (sh == 1) {
        pctx[0 * 512 + h] = c0; pctx[1 * 512 + h] = c1;
        pctx[2 * 512 + h] = c2; pctx[3 * 512 + h] = c3;
    }
    __syncthreads();
    if (sh == 0) {
        float* co = ctx_out + (size_t)(b * kTD + t0) * kH + h;
        co[0]       = c0 + pctx[0 * 512 + h];
        co[kH]      = c1 + pctx[1 * 512 + h];
        co[2 * kH]  = c2 + pctx[2 * 512 + h];
        co[3 * kH]  = c3 + pctx[3 * 512 + h];
    }
}

// ---------------------------------------------------------------------------
extern "C" void kernel_launch(void* const* d_in, const int* in_sizes, int n_in,
                              void* d_out, int out_size, void* d_ws, size_t ws_size,
                              hipStream_t stream) {
    const float* enc  = (const float*)d_in[0];   // [B, TE, H]
    const float* dec  = (const float*)d_in[1];   // [B, TD, H]
    const void*  mask = d_in[2];                 // [B, TE] bool
    const float* W1   = (const float*)d_in[3];
    const float* W2   = (const float*)d_in[4];
    const float* V    = (const float*)d_in[5];   // [H, 1]

    float* ctx_out  = (float*)d_out;                     // [B, TD, H]
    float* attn_out = (float*)d_out + kB * kTD * kH;     // [B, TD, TE]

    char* ws = (char*)d_ws;
    float* mask_f = (float*)ws;                                      // 2048 f
    float* ewt    = (float*)(ws + 8192);                             // E^T packed [b][h/4][s][4]
    float* dwc    = (float*)(ws + 8192 + (size_t)kB * kTE * kH * 4); // P[t][h]

    hipLaunchKernelGGL(prep_kernel, dim3(GEMM_BLOCKS + 1), dim3(256), 0, stream,
                       enc, dec, W1, W2, mask, ewt, dwc, mask_f);
    hipLaunchKernelGGL(fused_attn_kernel, dim3(kB * kTD / TM), dim3(1024), 0, stream,
                       ewt, dwc, enc, V, mask_f, ctx_out, attn_out);
}